// Round 12
// baseline (178.474 us; speedup 1.0000x reference)
//
#include <hip/hip_runtime.h>
#include <math.h>

// Problem constants
#define BB 8
#define LL 512
#define HH 768
#define PP 5
#define MM 32
#define DD 256
#define BL (BB*LL)          // 4096 rows
#define NCAT (3*HH)         // 2304 GEMM output cols
#define NSC (LL*PP)         // 2560 scores per batch
#define GK HH               // K = 768
#define NTAIL 640           // tail GEMM cols: 384 gate + 256 embed
#define NCAND 40            // cheap-selection candidates per batch
#define NCTOT (BB*NCAND)    // 320
#define KBIG 2304           // rescore K (start|end|mean)
#define RSPLIT 6            // rescore K-split (chunks of 384)
#define TSPLIT 3            // tail K-split (chunks of 256)

typedef short short8_t __attribute__((ext_vector_type(8)));
typedef float floatx4  __attribute__((ext_vector_type(4)));

// ---------------------------------------------------------------------------
__device__ __forceinline__ unsigned short f2bf_rne(float x) {
    unsigned u = __float_as_uint(x);
    unsigned r = u + 0x7FFFu + ((u >> 16) & 1u);
    return (unsigned short)(r >> 16);
}
__device__ __forceinline__ float bf2f(unsigned short h) {
    return __uint_as_float((unsigned)h << 16);
}

// ---------------------------------------------------------------------------
// fused pre-pass: A0 bf16 convert | B0 combo+convert (transposed) | lengths
__global__ __launch_bounds__(256) void prep_all(const float* __restrict__ hidden,
                                                const int* __restrict__ mask,
                                                const float* __restrict__ W1,
                                                unsigned short* __restrict__ A0,
                                                unsigned short* __restrict__ B0,
                                                int* __restrict__ lengths,
                                                int* __restrict__ nvalid) {
    int bid = blockIdx.x;
    if (bid < 3072) {
        size_t base = ((size_t)bid * 256 + threadIdx.x) * 4;
        float4 v = *(const float4*)(hidden + base);
        *(ushort4*)(A0 + base) = make_ushort4(f2bf_rne(v.x), f2bf_rne(v.y),
                                              f2bf_rne(v.z), f2bf_rne(v.w));
        return;
    }
    if (bid < 3072 + 1728) {
        int bb = bid - 3072;
        int n0 = (bb % 144) * 16;
        int k0 = (bb / 144) * 64;
        __shared__ float wv[16][65];
        int tx = threadIdx.x & 15;
        int ty = threadIdx.x >> 4;
        int n = n0 + tx;
        #pragma unroll
        for (int j = 0; j < 4; ++j) {
            int k = k0 + ty * 4 + j;
            float w;
            if (n < HH) {
                w = W1[(size_t)k * HH + n] - W1[(size_t)(3*HH + k) * HH + n];
            } else if (n < 2 * HH) {
                int c = n - HH;
                w = W1[(size_t)(HH + k) * HH + c] + W1[(size_t)(3*HH + k) * HH + c];
            } else {
                int c = n - 2 * HH;
                w = W1[(size_t)(2*HH + k) * HH + c];
            }
            wv[tx][ty * 4 + j] = w;
        }
        __syncthreads();
        int n2 = threadIdx.x >> 4;
        int kq = threadIdx.x & 15;
        ushort4 e;
        e.x = f2bf_rne(wv[n2][kq*4+0]); e.y = f2bf_rne(wv[n2][kq*4+1]);
        e.z = f2bf_rne(wv[n2][kq*4+2]); e.w = f2bf_rne(wv[n2][kq*4+3]);
        *(ushort4*)(B0 + (size_t)(n0 + n2) * GK + k0 + kq * 4) = e;
        return;
    }
    {
        int b = bid - 4800;
        int t = threadIdx.x;
        int v = mask[b*LL + t] + mask[b*LL + 256 + t];
        #pragma unroll
        for (int off = 32; off; off >>= 1) v += __shfl_xor(v, off);
        __shared__ int red[4];
        if ((t & 63) == 0) red[t >> 6] = v;
        __syncthreads();
        if (t == 0) {
            int len = red[0] + red[1] + red[2] + red[3];
            lengths[b] = len;
            int nv = 0;
            #pragma unroll
            for (int p = 0; p < PP; ++p) nv += (len - p > 0) ? (len - p) : 0;
            nvalid[b] = nv;
        }
    }
}

// ---------------------------------------------------------------------------
// 1-product bf16 MFMA GEMM (selection-grade): XO(bf16) = A0 x B0^T.
__global__ __launch_bounds__(256) void gemm_cheap(const unsigned short* __restrict__ A0,
                                                  const unsigned short* __restrict__ B0,
                                                  unsigned short* __restrict__ C) {
    __shared__ __align__(16) unsigned short Asm[128 * 64];
    __shared__ __align__(16) unsigned short Bsm[128 * 64];
    const int tid  = threadIdx.x;
    const int wave = tid >> 6;
    const int lane = tid & 63;
    const int m0 = blockIdx.x * 128;
    const int n0 = blockIdx.y * 128;
    const int wr = wave >> 1;
    const int wc = wave & 1;
    const int srow = lane >> 3;
    const int slog = (lane & 7) ^ srow;
    const int l15 = lane & 15;
    const int g   = lane >> 4;
    const int r7  = l15 & 7;

    floatx4 acc[4][4];
    #pragma unroll
    for (int i = 0; i < 4; ++i)
        #pragma unroll
        for (int j = 0; j < 4; ++j) acc[i][j] = (floatx4)0.f;

    const unsigned short* Ab = A0 + (size_t)m0 * GK;
    const unsigned short* Bb = B0 + (size_t)n0 * GK;

    #pragma unroll 1
    for (int kt = 0; kt < GK; kt += 64) {
        __syncthreads();
        #pragma unroll
        for (int j = 0; j < 4; ++j) {
            int base_r = (j * 4 + wave) * 8;
            const unsigned short* sa = Ab + (size_t)(base_r + srow) * GK + kt + slog * 8;
            __builtin_amdgcn_global_load_lds(
                (const __attribute__((address_space(1))) void*)sa,
                (__attribute__((address_space(3))) void*)&Asm[base_r * 64],
                16, 0, 0);
            const unsigned short* sb = Bb + (size_t)(base_r + srow) * GK + kt + slog * 8;
            __builtin_amdgcn_global_load_lds(
                (const __attribute__((address_space(1))) void*)sb,
                (__attribute__((address_space(3))) void*)&Bsm[base_r * 64],
                16, 0, 0);
        }
        __syncthreads();
        #pragma unroll
        for (int ks = 0; ks < 2; ++ks) {
            const int sph = ((ks * 4 + g) ^ r7) * 8;
            short8_t afr[4], bfr[4];
            #pragma unroll
            for (int mf = 0; mf < 4; ++mf)
                afr[mf] = *(const short8_t*)&Asm[(wr * 64 + mf * 16 + l15) * 64 + sph];
            #pragma unroll
            for (int nf = 0; nf < 4; ++nf)
                bfr[nf] = *(const short8_t*)&Bsm[(wc * 64 + nf * 16 + l15) * 64 + sph];
            #pragma unroll
            for (int mf = 0; mf < 4; ++mf)
                #pragma unroll
                for (int nf = 0; nf < 4; ++nf)
                    acc[mf][nf] = __builtin_amdgcn_mfma_f32_16x16x32_bf16(
                        afr[mf], bfr[nf], acc[mf][nf], 0, 0, 0);
        }
    }
    #pragma unroll
    for (int mf = 0; mf < 4; ++mf) {
        #pragma unroll
        for (int nf = 0; nf < 4; ++nf) {
            int col  = n0 + wc * 64 + nf * 16 + l15;
            int rowb = m0 + wr * 64 + mf * 16 + g * 4;
            #pragma unroll
            for (int e = 0; e < 4; ++e)
                C[(size_t)(rowb + e) * NCAT + col] = f2bf_rne(acc[mf][nf][e]);
        }
    }
}

// ---------------------------------------------------------------------------
// selection scores from bf16 XO; one wave per (b,l); unrolled p, clamped rows
__global__ __launch_bounds__(256) void score_kernel(const unsigned short* __restrict__ XO,
                                                    const float* __restrict__ b1,
                                                    const float* __restrict__ w2,
                                                    const float* __restrict__ b2,
                                                    const int* __restrict__ lengths,
                                                    float* __restrict__ sc) {
    int wid = (blockIdx.x * blockDim.x + threadIdx.x) >> 6;  // 0..4095
    int lane = threadIdx.x & 63;
    int b = wid >> 9, l = wid & (LL - 1);
    int len = lengths[b];

    if (l >= len) {
        if (lane == 0) {
            #pragma unroll
            for (int p = 0; p < PP; ++p) sc[(size_t)wid * PP + p] = -INFINITY;
        }
        return;
    }
    float b2v = b2[0];
    const unsigned short* rowXA = XO + (size_t)wid * NCAT;
    const unsigned short* rowbase = XO + (size_t)(b * LL) * NCAT;
    float xa[12], sv[12], w2v[12];
    #pragma unroll
    for (int seg = 0; seg < 3; ++seg) {
        int h = seg * 256 + lane * 4;
        ushort4 a  = *(const ushort4*)(rowXA + h);
        float4 bb = *(const float4*)(b1 + h);
        float4 w  = *(const float4*)(w2 + h);
        xa[seg*4+0] = bf2f(a.x) + bb.x; xa[seg*4+1] = bf2f(a.y) + bb.y;
        xa[seg*4+2] = bf2f(a.z) + bb.z; xa[seg*4+3] = bf2f(a.w) + bb.w;
        w2v[seg*4+0] = w.x; w2v[seg*4+1] = w.y; w2v[seg*4+2] = w.z; w2v[seg*4+3] = w.w;
        sv[seg*4+0] = 0.f; sv[seg*4+1] = 0.f; sv[seg*4+2] = 0.f; sv[seg*4+3] = 0.f;
    }

    float res[PP];
    #pragma unroll
    for (int p = 0; p < PP; ++p) {
        int j = l + p;
        int jc = (j < LL) ? j : (LL - 1);
        const unsigned short* rowj = rowbase + (size_t)jc * NCAT;
        float rs = 1.0f / (float)(p + 1);
        float part = 0.f;
        #pragma unroll
        for (int seg = 0; seg < 3; ++seg) {
            int h = seg * 256 + lane * 4;
            ushort4 xb = *(const ushort4*)(rowj + HH + h);
            ushort4 yv = *(const ushort4*)(rowj + 2*HH + h);
            sv[seg*4+0] += bf2f(yv.x); sv[seg*4+1] += bf2f(yv.y);
            sv[seg*4+2] += bf2f(yv.z); sv[seg*4+3] += bf2f(yv.w);
            float xbv[4] = {bf2f(xb.x), bf2f(xb.y), bf2f(xb.z), bf2f(xb.w)};
            #pragma unroll
            for (int q = 0; q < 4; ++q) {
                float pre = xa[seg*4+q] + xbv[q] + sv[seg*4+q] * rs;
                part += fmaxf(pre, 0.f) * w2v[seg*4+q];
            }
        }
        #pragma unroll
        for (int off = 32; off; off >>= 1) part += __shfl_xor(part, off);
        res[p] = (j < len) ? (part + b2v) : -INFINITY;
    }
    if (lane == 0) {
        #pragma unroll
        for (int p = 0; p < PP; ++p) sc[(size_t)wid * PP + p] = res[p];
    }
}

// ---------------------------------------------------------------------------
// top-40 SET per batch (unordered; rescore_rank orders by exact score later).
__global__ __launch_bounds__(64, 1) void topk_select(const float* __restrict__ sc,
                                                     int* __restrict__ cidx) {
    int b = blockIdx.x;
    int lane = threadIdx.x;
    const float* scb = sc + (size_t)b * NSC;

    unsigned u[40];
    #pragma unroll
    for (int j = 0; j < 40; ++j) {
        unsigned x = __float_as_uint(scb[j * 64 + lane]);
        u[j] = (x & 0x80000000u) ? ~x : (x | 0x80000000u);
    }

    unsigned lo = 0u, hi = 0xFFFFFFFFu;
    #pragma unroll 1
    for (int it = 0; it < 32; ++it) {
        if (lo >= hi) break;
        unsigned mid = (unsigned)(((unsigned long long)lo + hi + 1ull) >> 1);
        int cnt = 0;
        #pragma unroll
        for (int j = 0; j < 40; ++j) cnt += (u[j] >= mid) ? 1 : 0;
        #pragma unroll
        for (int off = 32; off; off >>= 1) cnt += __shfl_xor(cnt, off);
        if (cnt >= NCAND) lo = mid; else hi = mid - 1;
    }
    const unsigned T = lo;

    const unsigned long long lmask = (1ull << lane) - 1ull;  // bits strictly below
    int base = 0;
    #pragma unroll
    for (int j = 0; j < 40; ++j) {
        bool sel = (u[j] > T);
        unsigned long long m = __ballot(sel);
        if (sel) cidx[b * NCAND + base + __popcll(m & lmask)] = j * 64 + lane;
        base += __popcll(m);
    }
    #pragma unroll
    for (int j = 0; j < 40; ++j) {
        bool tie = (u[j] == T);
        unsigned long long m = __ballot(tie);
        if (tie) {
            int pos = base + __popcll(m & lmask);
            if (pos < NCAND) cidx[b * NCAND + pos] = j * 64 + lane;
        }
        base += __popcll(m);
    }
}

// ---------------------------------------------------------------------------
// K-SPLIT exact fp32 rescore partials, INLINE GATHER from hidden (no Z):
// grid (10, 12, RSPLIT). Each 384-chunk lies in one feature segment
// (seg = blockIdx.z/2): 0=start row l, 1=end row l+p, 2=mean rows l..l+p
// (sequential sum * rs -- bit-identical to the old zgather path).
__global__ __launch_bounds__(256) void rescore_part(const float* __restrict__ hidden,
                                                    const int* __restrict__ cidx,
                                                    const float* __restrict__ W1,
                                                    float* __restrict__ pre_part) {
    __shared__ __align__(16) float As[64][36];
    __shared__ __align__(16) float Bs[64][72];
    const int tid = threadIdx.x;
    const int m0 = blockIdx.x * 32;
    const int n0 = blockIdx.y * 64;
    const int kc = blockIdx.z * (KBIG / RSPLIT);
    const int seg = blockIdx.z >> 1;           // 0,1,2 (block-uniform)
    const int ty = tid >> 5;
    const int tx = tid & 31;

    float acc[4][2];
    #pragma unroll
    for (int r = 0; r < 4; ++r) { acc[r][0] = 0.f; acc[r][1] = 0.f; }

    const int ar = tid >> 3;
    const int ac = (tid & 7) * 4;
    const int br = tid >> 4;
    const int bc = (tid & 15) * 4;

    // per-thread candidate row (32 cands per block)
    const int arow = m0 + ar;
    const int flat = cidx[arow];
    const int l = flat / PP, p = flat % PP;
    const float rs = 1.0f / (float)(p + 1);
    const float* hb = hidden + (size_t)((arow / NCAND) * LL) * HH;

    for (int kt = kc; kt < kc + KBIG / RSPLIT; kt += 64) {
        int col = kt - seg * HH + ac;          // [0,768) base col for a0
        float4 a0, a1;
        if (seg == 0) {
            a0 = *(const float4*)(hb + (size_t)l * HH + col);
            a1 = *(const float4*)(hb + (size_t)l * HH + col + 32);
        } else if (seg == 1) {
            a0 = *(const float4*)(hb + (size_t)(l + p) * HH + col);
            a1 = *(const float4*)(hb + (size_t)(l + p) * HH + col + 32);
        } else {
            a0 = *(const float4*)(hb + (size_t)l * HH + col);
            a1 = *(const float4*)(hb + (size_t)l * HH + col + 32);
            for (int t = l + 1; t <= l + p; ++t) {
                float4 v0 = *(const float4*)(hb + (size_t)t * HH + col);
                float4 v1 = *(const float4*)(hb + (size_t)t * HH + col + 32);
                a0.x += v0.x; a0.y += v0.y; a0.z += v0.z; a0.w += v0.w;
                a1.x += v1.x; a1.y += v1.y; a1.z += v1.z; a1.w += v1.w;
            }
            a0.x *= rs; a0.y *= rs; a0.z *= rs; a0.w *= rs;
            a1.x *= rs; a1.y *= rs; a1.z *= rs; a1.w *= rs;
        }
        float4 bv[4];
        #pragma unroll
        for (int jj = 0; jj < 4; ++jj) {
            int f = kt + jj * 16 + br;
            float4 wmain = *(const float4*)(W1 + (size_t)f * HH + n0 + bc);
            if (seg == 0) {
                float4 waux = *(const float4*)(W1 + (size_t)(f + 3*HH) * HH + n0 + bc);
                wmain.x -= waux.x; wmain.y -= waux.y; wmain.z -= waux.z; wmain.w -= waux.w;
            } else if (seg == 1) {
                float4 waux = *(const float4*)(W1 + (size_t)(f + 2*HH) * HH + n0 + bc);
                wmain.x += waux.x; wmain.y += waux.y; wmain.z += waux.z; wmain.w += waux.w;
            }
            bv[jj] = wmain;
        }
        __syncthreads();
        As[ac+0][ar] = a0.x; As[ac+1][ar] = a0.y; As[ac+2][ar] = a0.z; As[ac+3][ar] = a0.w;
        As[ac+32][ar] = a1.x; As[ac+33][ar] = a1.y; As[ac+34][ar] = a1.z; As[ac+35][ar] = a1.w;
        #pragma unroll
        for (int jj = 0; jj < 4; ++jj)
            *(float4*)&Bs[jj * 16 + br][bc] = bv[jj];
        __syncthreads();
        #pragma unroll
        for (int k = 0; k < 64; ++k) {
            float4 a = *(const float4*)&As[k][ty * 4];
            float2 bvv = *(const float2*)&Bs[k][tx * 2];
            acc[0][0] = fmaf(a.x, bvv.x, acc[0][0]);
            acc[0][1] = fmaf(a.x, bvv.y, acc[0][1]);
            acc[1][0] = fmaf(a.y, bvv.x, acc[1][0]);
            acc[1][1] = fmaf(a.y, bvv.y, acc[1][1]);
            acc[2][0] = fmaf(a.z, bvv.x, acc[2][0]);
            acc[2][1] = fmaf(a.z, bvv.y, acc[2][1]);
            acc[3][0] = fmaf(a.w, bvv.x, acc[3][0]);
            acc[3][1] = fmaf(a.w, bvv.y, acc[3][1]);
        }
    }
    #pragma unroll
    for (int r = 0; r < 4; ++r) {
        int row = m0 + ty * 4 + r;
        float2 st = make_float2(acc[r][0], acc[r][1]);
        *(float2*)&pre_part[((size_t)blockIdx.z * NCTOT + row) * HH + n0 + tx * 2] = st;
    }
}

// ---------------------------------------------------------------------------
__device__ __forceinline__ unsigned long long wave_max_ull(unsigned long long v) {
    #pragma unroll
    for (int off = 32; off; off >>= 1) {
        unsigned long long o = __shfl_xor(v, off);
        if (o > v) v = o;
    }
    return v;
}

// ---------------------------------------------------------------------------
// FUSED rescore-combine + rerank: one block per batch (4 waves).
// Waves compute exact cand scores (sum 6 partials + b1 -> relu -> .w2);
// then wave 0 picks the final 32 of 40 (score desc, flat-idx asc on ties).
__global__ __launch_bounds__(256) void rescore_rank(const float* __restrict__ pre_part,
                                                    const float* __restrict__ b1,
                                                    const float* __restrict__ w2,
                                                    const float* __restrict__ b2,
                                                    const int* __restrict__ cidx,
                                                    int* __restrict__ selc,
                                                    float* __restrict__ tscoreF) {
    int b = blockIdx.x;
    int tid = threadIdx.x;
    int wv = tid >> 6, lane = tid & 63;
    __shared__ float cs[NCAND];
    float b2v = b2[0];
    for (int cc = wv; cc < NCAND; cc += 4) {
        int cand = b * NCAND + cc;
        float local = 0.f;
        #pragma unroll
        for (int hh = 0; hh < 12; ++hh) {
            int h = hh * 64 + lane;
            float pre = b1[h];
            #pragma unroll
            for (int z = 0; z < RSPLIT; ++z)
                pre += pre_part[((size_t)z * NCTOT + cand) * HH + h];
            local += fmaxf(pre, 0.f) * w2[h];
        }
        #pragma unroll
        for (int off = 32; off; off >>= 1) local += __shfl_xor(local, off);
        if (lane == 0) cs[cc] = local + b2v;
    }
    __syncthreads();
    if (tid < 64) {
        unsigned long long key = 0ull;
        float s = 0.f;
        if (lane < NCAND) {
            s = cs[lane];
            unsigned u = __float_as_uint(s);
            u = (u & 0x80000000u) ? ~u : (u | 0x80000000u);
            key = ((unsigned long long)u << 32) | (unsigned)(0xFFFFFFFFu - cidx[b * NCAND + lane]);
        }
        for (int m = 0; m < MM; ++m) {
            unsigned long long best = wave_max_ull(key);
            if (key == best && key != 0ull) {
                selc[b * MM + m] = b * NCAND + lane;
                tscoreF[b * MM + m] = s;
                key = 0ull;
            }
        }
    }
}

// ---------------------------------------------------------------------------
// K-SPLIT tail GEMM partials, INLINE mean gather (no Z):
// F(256x768 = mean feats of selected) @ [Wg1|Wp]. grid (8, 10, TSPLIT).
__global__ __launch_bounds__(256) void tail_part(const float* __restrict__ hidden,
                                                 const int* __restrict__ cidx,
                                                 const int* __restrict__ selc,
                                                 const int* __restrict__ nvalid,
                                                 const float* __restrict__ Wg1,
                                                 const float* __restrict__ Wp,
                                                 float* __restrict__ tpart) {
    __shared__ __align__(16) float As[64][36];
    __shared__ __align__(16) float Bs[64][72];
    const int tid = threadIdx.x;
    const int m0 = blockIdx.x * 32;
    const int n0 = blockIdx.y * 64;
    const int kc = blockIdx.z * (GK / TSPLIT);
    const int ty = tid >> 5;
    const int tx = tid & 31;

    float acc[4][2];
    #pragma unroll
    for (int r = 0; r < 4; ++r) { acc[r][0] = 0.f; acc[r][1] = 0.f; }

    const int ar = tid >> 3;
    const int ac = (tid & 7) * 4;
    const int br = tid >> 4;
    const int bc = (tid & 15) * 4;

    const int arow = m0 + ar;
    const float amul = ((arow & 31) < nvalid[arow >> 5]) ? 1.f : 0.f;
    const int cand = selc[arow];
    const int flat = cidx[cand];
    const int l = flat / PP, p = flat % PP;
    const float rs = 1.0f / (float)(p + 1);
    const float* hb = hidden + (size_t)((cand / NCAND) * LL) * HH;
    const bool isGate = (n0 < 384);

    for (int kt = kc; kt < kc + GK / TSPLIT; kt += 64) {
        int col = kt + ac;
        float4 a0 = *(const float4*)(hb + (size_t)l * HH + col);
        float4 a1 = *(const float4*)(hb + (size_t)l * HH + col + 32);
        for (int t = l + 1; t <= l + p; ++t) {
            float4 v0 = *(const float4*)(hb + (size_t)t * HH + col);
            float4 v1 = *(const float4*)(hb + (size_t)t * HH + col + 32);
            a0.x += v0.x; a0.y += v0.y; a0.z += v0.z; a0.w += v0.w;
            a1.x += v1.x; a1.y += v1.y; a1.z += v1.z; a1.w += v1.w;
        }
        float sm = rs * amul;
        float4 bv[4];
        #pragma unroll
        for (int jj = 0; jj < 4; ++jj) {
            int f = kt + jj * 16 + br;
            if (isGate) bv[jj] = *(const float4*)(Wg1 + (size_t)f * 384 + n0 + bc);
            else        bv[jj] = *(const float4*)(Wp  + (size_t)f * DD  + (n0 - 384) + bc);
        }
        __syncthreads();
        As[ac+0][ar] = a0.x * sm; As[ac+1][ar] = a0.y * sm;
        As[ac+2][ar] = a0.z * sm; As[ac+3][ar] = a0.w * sm;
        As[ac+32][ar] = a1.x * sm; As[ac+33][ar] = a1.y * sm;
        As[ac+34][ar] = a1.z * sm; As[ac+35][ar] = a1.w * sm;
        #pragma unroll
        for (int jj = 0; jj < 4; ++jj)
            *(float4*)&Bs[jj * 16 + br][bc] = bv[jj];
        __syncthreads();
        #pragma unroll
        for (int k = 0; k < 64; ++k) {
            float4 a = *(const float4*)&As[k][ty * 4];
            float2 bvv = *(const float2*)&Bs[k][tx * 2];
            acc[0][0] = fmaf(a.x, bvv.x, acc[0][0]);
            acc[0][1] = fmaf(a.x, bvv.y, acc[0][1]);
            acc[1][0] = fmaf(a.y, bvv.x, acc[1][0]);
            acc[1][1] = fmaf(a.y, bvv.y, acc[1][1]);
            acc[2][0] = fmaf(a.z, bvv.x, acc[2][0]);
            acc[2][1] = fmaf(a.z, bvv.y, acc[2][1]);
            acc[3][0] = fmaf(a.w, bvv.x, acc[3][0]);
            acc[3][1] = fmaf(a.w, bvv.y, acc[3][1]);
        }
    }
    #pragma unroll
    for (int r = 0; r < 4; ++r) {
        int row = m0 + ty * 4 + r;
        float2 st = make_float2(acc[r][0], acc[r][1]);
        *(float2*)&tpart[((size_t)blockIdx.z * (BB*MM) + row) * NTAIL + n0 + tx * 2] = st;
    }
}

// ---------------------------------------------------------------------------
// FUSED tail-combine + finalize: one block per batch (4 waves x 8 rows).
// Per row: sum TSPLIT partials; gate cols -> tanh(+bg1)*wg2 wave-reduce;
// embed cols -> +bp -> out_embeds. Then masks + softmax + masked scores.
__global__ __launch_bounds__(256) void tail_finalize(const float* __restrict__ tpart,
                                                     const float* __restrict__ bg1,
                                                     const float* __restrict__ wg2,
                                                     const float* __restrict__ bg2,
                                                     const float* __restrict__ bp,
                                                     const float* __restrict__ tscoreF,
                                                     const int* __restrict__ nvalid,
                                                     float* __restrict__ out_embeds,
                                                     float* __restrict__ out_masks,
                                                     float* __restrict__ out_attn,
                                                     float* __restrict__ out_scores) {
    int b = blockIdx.x;
    int tid = threadIdx.x;
    int wv = tid >> 6, lane = tid & 63;
    __shared__ float gsh[MM];
    float bg2v = bg2[0];
    #pragma unroll
    for (int r8 = 0; r8 < 8; ++r8) {
        int m = wv * 8 + r8;
        size_t row = (size_t)(b * MM + m);
        float gpart = 0.f;
        #pragma unroll
        for (int s6 = 0; s6 < 6; ++s6) {
            int c = s6 * 64 + lane;
            float pre = tpart[row * NTAIL + c]
                      + tpart[((size_t)(BB*MM) + row) * NTAIL + c]
                      + tpart[((size_t)(2*BB*MM) + row) * NTAIL + c];
            gpart += tanhf(pre + bg1[c]) * wg2[c];
        }
        #pragma unroll
        for (int s4 = 0; s4 < 4; ++s4) {
            int c = 384 + s4 * 64 + lane;
            float pre = tpart[row * NTAIL + c]
                      + tpart[((size_t)(BB*MM) + row) * NTAIL + c]
                      + tpart[((size_t)(2*BB*MM) + row) * NTAIL + c];
            out_embeds[row * DD + (c - 384)] = pre + bp[c - 384];
        }
        #pragma unroll
        for (int off = 32; off; off >>= 1) gpart += __shfl_xor(gpart, off);
        if (lane == 0) gsh[m] = gpart + bg2v;
    }
    __syncthreads();
    if (tid < MM) {
        bool maskon = tid < nvalid[b];
        float g = maskon ? gsh[tid] : -INFINITY;
        float mx = g;
        #pragma unroll
        for (int off = 16; off; off >>= 1) mx = fmaxf(mx, __shfl_xor(mx, off));
        float e = (g == -INFINITY) ? 0.f : expf(g - mx);
        float ssum = e;
        #pragma unroll
        for (int off = 16; off; off >>= 1) ssum += __shfl_xor(ssum, off);
        out_masks[b * MM + tid]  = maskon ? 1.0f : 0.0f;
        out_attn[b * MM + tid]   = e / ssum;
        out_scores[b * MM + tid] = maskon ? tscoreF[b * MM + tid] : -INFINITY;
    }
}

// ---------------------------------------------------------------------------
extern "C" void kernel_launch(void* const* d_in, const int* in_sizes, int n_in,
                              void* d_out, int out_size, void* d_ws, size_t ws_size,
                              hipStream_t stream) {
    const float* hidden = (const float*)d_in[0];
    const int*   amask  = (const int*)  d_in[1];
    const float* W1     = (const float*)d_in[2];
    const float* b1     = (const float*)d_in[3];
    const float* w2     = (const float*)d_in[4];
    const float* b2     = (const float*)d_in[5];
    const float* Wg1    = (const float*)d_in[6];
    const float* bg1    = (const float*)d_in[7];
    const float* wg2    = (const float*)d_in[8];
    const float* bg2    = (const float*)d_in[9];
    const float* Wp     = (const float*)d_in[10];
    const float* bp     = (const float*)d_in[11];

    float* out = (float*)d_out;
    float* out_embeds = out;                       // 8*32*256 = 65536
    float* out_masks  = out + 65536;               // 256
    float* out_attn   = out + 65792;               // 256
    float* out_scores = out + 66048;               // 256

    // workspace layout
    unsigned short* A0  = (unsigned short*)d_ws;               // 4096*768 bf16
    unsigned short* B0  = A0 + (size_t)BL * GK;                // 2304*768 bf16
    unsigned short* XOh = B0 + (size_t)NCAT * GK;              // 4096*2304 bf16 (18.9 MB)
    float* scbuf = (float*)(XOh + (size_t)BL * NCAT);          // 8*2560
    int*   cidx  = (int*)(scbuf + (size_t)BB * NSC);           // 320
    int*   selc  = cidx + NCTOT;                               // 256
    float* tsF   = (float*)(selc + BB * MM);                   // 256
    int*   lengths = (int*)(tsF + BB * MM);                    // 8
    int*   nvalid  = lengths + BB;                             // 8
    // aliased into XOh region (dead after topk_select): 5.9 + 2.0 MB < 18.9 MB
    float* pre_part = (float*)XOh;                             // 6*320*768
    float* tpart    = pre_part + (size_t)RSPLIT * NCTOT * HH;  // 3*256*640

    prep_all<<<3072 + 1728 + BB, 256, 0, stream>>>(hidden, amask, W1, A0, B0,
                                                   lengths, nvalid);

    {
        dim3 grid(BL / 128, NCAT / 128);   // 32 x 18
        gemm_cheap<<<grid, 256, 0, stream>>>(A0, B0, XOh);
    }

    score_kernel<<<(BL * 64) / 256, 256, 0, stream>>>(XOh, b1, w2, b2, lengths, scbuf);

    topk_select<<<BB, 64, 0, stream>>>(scbuf, cidx);

    {
        dim3 grid(NCTOT / 32, HH / 64, RSPLIT);    // 10 x 12 x 6
        rescore_part<<<grid, 256, 0, stream>>>(hidden, cidx, W1, pre_part);
    }

    rescore_rank<<<BB, 256, 0, stream>>>(pre_part, b1, w2, b2, cidx, selc, tsF);

    {
        dim3 grid(BB * MM / 32, NTAIL / 64, TSPLIT);   // 8 x 10 x 3
        tail_part<<<grid, 256, 0, stream>>>(hidden, cidx, selc, nvalid, Wg1, Wp, tpart);
    }

    tail_finalize<<<BB, 256, 0, stream>>>(tpart, bg1, wg2, bg2, bp, tsF, nvalid,
                                          out_embeds, out_masks, out_attn, out_scores);
}

// Round 13
// 134.866 us; speedup vs baseline: 1.3233x; 1.3233x over previous
//
#include <hip/hip_runtime.h>
#include <math.h>

// Problem constants
#define BB 8
#define LL 512
#define HH 768
#define PP 5
#define MM 32
#define DD 256
#define BL (BB*LL)          // 4096 rows
#define NCAT (3*HH)         // 2304 GEMM output cols
#define NSC (LL*PP)         // 2560 scores per batch
#define GK HH               // K = 768
#define NTAIL 640           // tail GEMM cols: 384 gate + 256 embed
#define NCAND 40            // cheap-selection candidates per batch
#define NCTOT (BB*NCAND)    // 320
#define KBIG 2304           // rescore K (start|end|mean)
#define RSPLIT 6            // rescore K-split (chunks of 384)
#define TSPLIT 3            // tail K-split (chunks of 256)

// R12 LESSON (reverted): fusing combine-stages down to 8 blocks starved the
// chip (32 waves / 256 CUs) and inline gathers added redundant work -> +43us.
// This file is the R11 structure: every kernel >= 240 blocks or trivially
// cheap; combine stages keep 256-320 block parallelism.

typedef short short8_t __attribute__((ext_vector_type(8)));
typedef float floatx4  __attribute__((ext_vector_type(4)));

// ---------------------------------------------------------------------------
__device__ __forceinline__ unsigned short f2bf_rne(float x) {
    unsigned u = __float_as_uint(x);
    unsigned r = u + 0x7FFFu + ((u >> 16) & 1u);
    return (unsigned short)(r >> 16);
}
__device__ __forceinline__ float bf2f(unsigned short h) {
    return __uint_as_float((unsigned)h << 16);
}

// ---------------------------------------------------------------------------
// fused pre-pass: A0 bf16 convert | B0 combo+convert (transposed) | lengths
__global__ __launch_bounds__(256) void prep_all(const float* __restrict__ hidden,
                                                const int* __restrict__ mask,
                                                const float* __restrict__ W1,
                                                unsigned short* __restrict__ A0,
                                                unsigned short* __restrict__ B0,
                                                int* __restrict__ lengths,
                                                int* __restrict__ nvalid) {
    int bid = blockIdx.x;
    if (bid < 3072) {
        size_t base = ((size_t)bid * 256 + threadIdx.x) * 4;
        float4 v = *(const float4*)(hidden + base);
        *(ushort4*)(A0 + base) = make_ushort4(f2bf_rne(v.x), f2bf_rne(v.y),
                                              f2bf_rne(v.z), f2bf_rne(v.w));
        return;
    }
    if (bid < 3072 + 1728) {
        int bb = bid - 3072;
        int n0 = (bb % 144) * 16;
        int k0 = (bb / 144) * 64;
        __shared__ float wv[16][65];
        int tx = threadIdx.x & 15;
        int ty = threadIdx.x >> 4;
        int n = n0 + tx;
        #pragma unroll
        for (int j = 0; j < 4; ++j) {
            int k = k0 + ty * 4 + j;
            float w;
            if (n < HH) {
                w = W1[(size_t)k * HH + n] - W1[(size_t)(3*HH + k) * HH + n];
            } else if (n < 2 * HH) {
                int c = n - HH;
                w = W1[(size_t)(HH + k) * HH + c] + W1[(size_t)(3*HH + k) * HH + c];
            } else {
                int c = n - 2 * HH;
                w = W1[(size_t)(2*HH + k) * HH + c];
            }
            wv[tx][ty * 4 + j] = w;
        }
        __syncthreads();
        int n2 = threadIdx.x >> 4;
        int kq = threadIdx.x & 15;
        ushort4 e;
        e.x = f2bf_rne(wv[n2][kq*4+0]); e.y = f2bf_rne(wv[n2][kq*4+1]);
        e.z = f2bf_rne(wv[n2][kq*4+2]); e.w = f2bf_rne(wv[n2][kq*4+3]);
        *(ushort4*)(B0 + (size_t)(n0 + n2) * GK + k0 + kq * 4) = e;
        return;
    }
    {
        int b = bid - 4800;
        int t = threadIdx.x;
        int v = mask[b*LL + t] + mask[b*LL + 256 + t];
        #pragma unroll
        for (int off = 32; off; off >>= 1) v += __shfl_xor(v, off);
        __shared__ int red[4];
        if ((t & 63) == 0) red[t >> 6] = v;
        __syncthreads();
        if (t == 0) {
            int len = red[0] + red[1] + red[2] + red[3];
            lengths[b] = len;
            int nv = 0;
            #pragma unroll
            for (int p = 0; p < PP; ++p) nv += (len - p > 0) ? (len - p) : 0;
            nvalid[b] = nv;
        }
    }
}

// ---------------------------------------------------------------------------
// 1-product bf16 MFMA GEMM (selection-grade): XO(bf16) = A0 x B0^T.
// R5 structure; epilogue stores bf16 (XO only feeds selection -- exact
// rescore recomputes in fp32; rounding adds ~1.2e-3 << 0.08 selection margin).
__global__ __launch_bounds__(256) void gemm_cheap(const unsigned short* __restrict__ A0,
                                                  const unsigned short* __restrict__ B0,
                                                  unsigned short* __restrict__ C) {
    __shared__ __align__(16) unsigned short Asm[128 * 64];
    __shared__ __align__(16) unsigned short Bsm[128 * 64];
    const int tid  = threadIdx.x;
    const int wave = tid >> 6;
    const int lane = tid & 63;
    const int m0 = blockIdx.x * 128;
    const int n0 = blockIdx.y * 128;
    const int wr = wave >> 1;
    const int wc = wave & 1;
    const int srow = lane >> 3;
    const int slog = (lane & 7) ^ srow;
    const int l15 = lane & 15;
    const int g   = lane >> 4;
    const int r7  = l15 & 7;

    floatx4 acc[4][4];
    #pragma unroll
    for (int i = 0; i < 4; ++i)
        #pragma unroll
        for (int j = 0; j < 4; ++j) acc[i][j] = (floatx4)0.f;

    const unsigned short* Ab = A0 + (size_t)m0 * GK;
    const unsigned short* Bb = B0 + (size_t)n0 * GK;

    #pragma unroll 1
    for (int kt = 0; kt < GK; kt += 64) {
        __syncthreads();
        #pragma unroll
        for (int j = 0; j < 4; ++j) {
            int base_r = (j * 4 + wave) * 8;
            const unsigned short* sa = Ab + (size_t)(base_r + srow) * GK + kt + slog * 8;
            __builtin_amdgcn_global_load_lds(
                (const __attribute__((address_space(1))) void*)sa,
                (__attribute__((address_space(3))) void*)&Asm[base_r * 64],
                16, 0, 0);
            const unsigned short* sb = Bb + (size_t)(base_r + srow) * GK + kt + slog * 8;
            __builtin_amdgcn_global_load_lds(
                (const __attribute__((address_space(1))) void*)sb,
                (__attribute__((address_space(3))) void*)&Bsm[base_r * 64],
                16, 0, 0);
        }
        __syncthreads();
        #pragma unroll
        for (int ks = 0; ks < 2; ++ks) {
            const int sph = ((ks * 4 + g) ^ r7) * 8;
            short8_t afr[4], bfr[4];
            #pragma unroll
            for (int mf = 0; mf < 4; ++mf)
                afr[mf] = *(const short8_t*)&Asm[(wr * 64 + mf * 16 + l15) * 64 + sph];
            #pragma unroll
            for (int nf = 0; nf < 4; ++nf)
                bfr[nf] = *(const short8_t*)&Bsm[(wc * 64 + nf * 16 + l15) * 64 + sph];
            #pragma unroll
            for (int mf = 0; mf < 4; ++mf)
                #pragma unroll
                for (int nf = 0; nf < 4; ++nf)
                    acc[mf][nf] = __builtin_amdgcn_mfma_f32_16x16x32_bf16(
                        afr[mf], bfr[nf], acc[mf][nf], 0, 0, 0);
        }
    }
    #pragma unroll
    for (int mf = 0; mf < 4; ++mf) {
        #pragma unroll
        for (int nf = 0; nf < 4; ++nf) {
            int col  = n0 + wc * 64 + nf * 16 + l15;
            int rowb = m0 + wr * 64 + mf * 16 + g * 4;
            #pragma unroll
            for (int e = 0; e < 4; ++e)
                C[(size_t)(rowb + e) * NCAT + col] = f2bf_rne(acc[mf][nf][e]);
        }
    }
}

// ---------------------------------------------------------------------------
// selection scores from bf16 XO; one wave per (b,l); unrolled p, clamped rows
__global__ __launch_bounds__(256) void score_kernel(const unsigned short* __restrict__ XO,
                                                    const float* __restrict__ b1,
                                                    const float* __restrict__ w2,
                                                    const float* __restrict__ b2,
                                                    const int* __restrict__ lengths,
                                                    float* __restrict__ sc) {
    int wid = (blockIdx.x * blockDim.x + threadIdx.x) >> 6;  // 0..4095
    int lane = threadIdx.x & 63;
    int b = wid >> 9, l = wid & (LL - 1);
    int len = lengths[b];

    if (l >= len) {
        if (lane == 0) {
            #pragma unroll
            for (int p = 0; p < PP; ++p) sc[(size_t)wid * PP + p] = -INFINITY;
        }
        return;
    }
    float b2v = b2[0];
    const unsigned short* rowXA = XO + (size_t)wid * NCAT;
    const unsigned short* rowbase = XO + (size_t)(b * LL) * NCAT;
    float xa[12], sv[12], w2v[12];
    #pragma unroll
    for (int seg = 0; seg < 3; ++seg) {
        int h = seg * 256 + lane * 4;
        ushort4 a  = *(const ushort4*)(rowXA + h);
        float4 bb = *(const float4*)(b1 + h);
        float4 w  = *(const float4*)(w2 + h);
        xa[seg*4+0] = bf2f(a.x) + bb.x; xa[seg*4+1] = bf2f(a.y) + bb.y;
        xa[seg*4+2] = bf2f(a.z) + bb.z; xa[seg*4+3] = bf2f(a.w) + bb.w;
        w2v[seg*4+0] = w.x; w2v[seg*4+1] = w.y; w2v[seg*4+2] = w.z; w2v[seg*4+3] = w.w;
        sv[seg*4+0] = 0.f; sv[seg*4+1] = 0.f; sv[seg*4+2] = 0.f; sv[seg*4+3] = 0.f;
    }

    float res[PP];
    #pragma unroll
    for (int p = 0; p < PP; ++p) {
        int j = l + p;
        int jc = (j < LL) ? j : (LL - 1);
        const unsigned short* rowj = rowbase + (size_t)jc * NCAT;
        float rs = 1.0f / (float)(p + 1);
        float part = 0.f;
        #pragma unroll
        for (int seg = 0; seg < 3; ++seg) {
            int h = seg * 256 + lane * 4;
            ushort4 xb = *(const ushort4*)(rowj + HH + h);
            ushort4 yv = *(const ushort4*)(rowj + 2*HH + h);
            sv[seg*4+0] += bf2f(yv.x); sv[seg*4+1] += bf2f(yv.y);
            sv[seg*4+2] += bf2f(yv.z); sv[seg*4+3] += bf2f(yv.w);
            float xbv[4] = {bf2f(xb.x), bf2f(xb.y), bf2f(xb.z), bf2f(xb.w)};
            #pragma unroll
            for (int q = 0; q < 4; ++q) {
                float pre = xa[seg*4+q] + xbv[q] + sv[seg*4+q] * rs;
                part += fmaxf(pre, 0.f) * w2v[seg*4+q];
            }
        }
        #pragma unroll
        for (int off = 32; off; off >>= 1) part += __shfl_xor(part, off);
        res[p] = (j < len) ? (part + b2v) : -INFINITY;
    }
    if (lane == 0) {
        #pragma unroll
        for (int p = 0; p < PP; ++p) sc[(size_t)wid * PP + p] = res[p];
    }
}

// ---------------------------------------------------------------------------
// top-40 SET per batch (unordered; rerank orders by exact score later).
// One wave/batch; 2560 encoded 32-bit scores in registers (40 u32/lane,
// static index; __launch_bounds__(64,1) so the allocator doesn't spill).
// 32-iteration binary search for the 40th-largest VALUE; ties at T filled
// in increasing flat-idx order -> matches lax.top_k set semantics.
__global__ __launch_bounds__(64, 1) void topk_select(const float* __restrict__ sc,
                                                     int* __restrict__ cidx) {
    int b = blockIdx.x;
    int lane = threadIdx.x;
    const float* scb = sc + (size_t)b * NSC;

    unsigned u[40];
    #pragma unroll
    for (int j = 0; j < 40; ++j) {
        unsigned x = __float_as_uint(scb[j * 64 + lane]);
        u[j] = (x & 0x80000000u) ? ~x : (x | 0x80000000u);
    }

    unsigned lo = 0u, hi = 0xFFFFFFFFu;
    #pragma unroll 1
    for (int it = 0; it < 32; ++it) {
        if (lo >= hi) break;
        unsigned mid = (unsigned)(((unsigned long long)lo + hi + 1ull) >> 1);
        int cnt = 0;
        #pragma unroll
        for (int j = 0; j < 40; ++j) cnt += (u[j] >= mid) ? 1 : 0;
        #pragma unroll
        for (int off = 32; off; off >>= 1) cnt += __shfl_xor(cnt, off);
        if (cnt >= NCAND) lo = mid; else hi = mid - 1;
    }
    const unsigned T = lo;

    const unsigned long long lmask = (1ull << lane) - 1ull;  // bits strictly below
    int base = 0;
    #pragma unroll
    for (int j = 0; j < 40; ++j) {
        bool sel = (u[j] > T);
        unsigned long long m = __ballot(sel);
        if (sel) cidx[b * NCAND + base + __popcll(m & lmask)] = j * 64 + lane;
        base += __popcll(m);
    }
    #pragma unroll
    for (int j = 0; j < 40; ++j) {
        bool tie = (u[j] == T);
        unsigned long long m = __ballot(tie);
        if (tie) {
            int pos = base + __popcll(m & lmask);
            if (pos < NCAND) cidx[b * NCAND + pos] = j * 64 + lane;
        }
        base += __popcll(m);
    }
}

// ---------------------------------------------------------------------------
// Z[cand][2304] = [start | end | mean] gathered from hidden (fp32)
__global__ __launch_bounds__(256) void zgather(const float* __restrict__ hidden,
                                               const int* __restrict__ cidx,
                                               float* __restrict__ Z) {
    int cand = blockIdx.x;              // 0..319
    int b = cand / NCAND;
    int flat = cidx[cand];
    int l = flat / PP, p = flat % PP;
    float rs = 1.0f / (float)(p + 1);
    const float* hb = hidden + (size_t)(b * LL) * HH;
    float* zr = Z + (size_t)cand * KBIG;
    for (int h = threadIdx.x; h < HH; h += 256) {
        float s = hb[(size_t)l * HH + h];
        float sum = s;
        for (int t = l + 1; t <= l + p; ++t) sum += hb[(size_t)t * HH + h];
        zr[h]          = s;
        zr[HH + h]     = hb[(size_t)(l + p) * HH + h];
        zr[2*HH + h]   = sum * rs;
    }
}

// ---------------------------------------------------------------------------
// K-SPLIT exact fp32 rescore partials: grid (10, 12, RSPLIT).
__global__ __launch_bounds__(256) void rescore_part(const float* __restrict__ Z,
                                                    const float* __restrict__ W1,
                                                    float* __restrict__ pre_part) {
    __shared__ __align__(16) float As[64][36];
    __shared__ __align__(16) float Bs[64][72];
    const int tid = threadIdx.x;
    const int m0 = blockIdx.x * 32;
    const int n0 = blockIdx.y * 64;
    const int kc = blockIdx.z * (KBIG / RSPLIT);
    const int ty = tid >> 5;
    const int tx = tid & 31;

    float acc[4][2];
    #pragma unroll
    for (int r = 0; r < 4; ++r) { acc[r][0] = 0.f; acc[r][1] = 0.f; }

    const int ar = tid >> 3;
    const int ac = (tid & 7) * 4;
    const int br = tid >> 4;
    const int bc = (tid & 15) * 4;

    for (int kt = kc; kt < kc + KBIG / RSPLIT; kt += 64) {
        float4 a0 = *(const float4*)(Z + (size_t)(m0 + ar) * KBIG + kt + ac);
        float4 a1 = *(const float4*)(Z + (size_t)(m0 + ar) * KBIG + kt + ac + 32);
        int seg = kt / HH;
        float4 bv[4];
        #pragma unroll
        for (int jj = 0; jj < 4; ++jj) {
            int f = kt + jj * 16 + br;
            float4 wmain = *(const float4*)(W1 + (size_t)f * HH + n0 + bc);
            if (seg == 0) {
                float4 waux = *(const float4*)(W1 + (size_t)(f + 3*HH) * HH + n0 + bc);
                wmain.x -= waux.x; wmain.y -= waux.y; wmain.z -= waux.z; wmain.w -= waux.w;
            } else if (seg == 1) {
                float4 waux = *(const float4*)(W1 + (size_t)(f + 2*HH) * HH + n0 + bc);
                wmain.x += waux.x; wmain.y += waux.y; wmain.z += waux.z; wmain.w += waux.w;
            }
            bv[jj] = wmain;
        }
        __syncthreads();
        As[ac+0][ar] = a0.x; As[ac+1][ar] = a0.y; As[ac+2][ar] = a0.z; As[ac+3][ar] = a0.w;
        As[ac+32][ar] = a1.x; As[ac+33][ar] = a1.y; As[ac+34][ar] = a1.z; As[ac+35][ar] = a1.w;
        #pragma unroll
        for (int jj = 0; jj < 4; ++jj)
            *(float4*)&Bs[jj * 16 + br][bc] = bv[jj];
        __syncthreads();
        #pragma unroll
        for (int k = 0; k < 64; ++k) {
            float4 a = *(const float4*)&As[k][ty * 4];
            float2 bvv = *(const float2*)&Bs[k][tx * 2];
            acc[0][0] = fmaf(a.x, bvv.x, acc[0][0]);
            acc[0][1] = fmaf(a.x, bvv.y, acc[0][1]);
            acc[1][0] = fmaf(a.y, bvv.x, acc[1][0]);
            acc[1][1] = fmaf(a.y, bvv.y, acc[1][1]);
            acc[2][0] = fmaf(a.z, bvv.x, acc[2][0]);
            acc[2][1] = fmaf(a.z, bvv.y, acc[2][1]);
            acc[3][0] = fmaf(a.w, bvv.x, acc[3][0]);
            acc[3][1] = fmaf(a.w, bvv.y, acc[3][1]);
        }
    }
    #pragma unroll
    for (int r = 0; r < 4; ++r) {
        int row = m0 + ty * 4 + r;
        float2 st = make_float2(acc[r][0], acc[r][1]);
        *(float2*)&pre_part[((size_t)blockIdx.z * NCTOT + row) * HH + n0 + tx * 2] = st;
    }
}

// ---------------------------------------------------------------------------
// combine partials -> exact candidate scores: one block per cand
__global__ __launch_bounds__(256) void rescore_fin(const float* __restrict__ pre_part,
                                                   const float* __restrict__ b1,
                                                   const float* __restrict__ w2,
                                                   const float* __restrict__ b2,
                                                   float* __restrict__ cscore) {
    int cand = blockIdx.x;
    int tid = threadIdx.x;
    float local = 0.f;
    #pragma unroll
    for (int hh = 0; hh < 3; ++hh) {
        int h = hh * 256 + tid;
        float pre = b1[h];
        #pragma unroll
        for (int z = 0; z < RSPLIT; ++z)
            pre += pre_part[((size_t)z * NCTOT + cand) * HH + h];
        local += fmaxf(pre, 0.f) * w2[h];
    }
    #pragma unroll
    for (int off = 32; off; off >>= 1) local += __shfl_xor(local, off);
    __shared__ float red[4];
    if ((tid & 63) == 0) red[tid >> 6] = local;
    __syncthreads();
    if (tid == 0) cscore[cand] = red[0] + red[1] + red[2] + red[3] + b2[0];
}

// ---------------------------------------------------------------------------
__device__ __forceinline__ unsigned long long wave_max_ull(unsigned long long v) {
    #pragma unroll
    for (int off = 32; off; off >>= 1) {
        unsigned long long o = __shfl_xor(v, off);
        if (o > v) v = o;
    }
    return v;
}

// ---------------------------------------------------------------------------
// rerank: pick final 32 of 40 by exact score (desc, flat-idx asc on ties)
__global__ __launch_bounds__(64) void rerank(const float* __restrict__ cscore,
                                             const int* __restrict__ cidx,
                                             int* __restrict__ selc,
                                             float* __restrict__ tscoreF) {
    int b = blockIdx.x;
    int lane = threadIdx.x;
    unsigned long long key = 0ull;
    float s = 0.f;
    int mycand = b * NCAND + lane;
    if (lane < NCAND) {
        s = cscore[mycand];
        unsigned u = __float_as_uint(s);
        u = (u & 0x80000000u) ? ~u : (u | 0x80000000u);
        key = ((unsigned long long)u << 32) | (unsigned)(0xFFFFFFFFu - cidx[mycand]);
    }
    for (int m = 0; m < MM; ++m) {
        unsigned long long best = wave_max_ull(key);
        if (key == best && key != 0ull) {
            selc[b * MM + m] = mycand;
            tscoreF[b * MM + m] = s;
            key = 0ull;
        }
    }
}

// ---------------------------------------------------------------------------
// K-SPLIT tail GEMM partials: F(256x768 = Z mean seg of selected) @ [Wg1|Wp].
__global__ __launch_bounds__(256) void tail_part(const float* __restrict__ Z,
                                                 const int* __restrict__ selc,
                                                 const int* __restrict__ nvalid,
                                                 const float* __restrict__ Wg1,
                                                 const float* __restrict__ Wp,
                                                 float* __restrict__ tpart) {
    __shared__ __align__(16) float As[64][36];
    __shared__ __align__(16) float Bs[64][72];
    const int tid = threadIdx.x;
    const int m0 = blockIdx.x * 32;
    const int n0 = blockIdx.y * 64;
    const int kc = blockIdx.z * (GK / TSPLIT);
    const int ty = tid >> 5;
    const int tx = tid & 31;

    float acc[4][2];
    #pragma unroll
    for (int r = 0; r < 4; ++r) { acc[r][0] = 0.f; acc[r][1] = 0.f; }

    const int ar = tid >> 3;
    const int ac = (tid & 7) * 4;
    const int br = tid >> 4;
    const int bc = (tid & 15) * 4;

    int arow = m0 + ar;
    float amul = ((arow & 31) < nvalid[arow >> 5]) ? 1.f : 0.f;
    const float* Frow = Z + (size_t)selc[arow] * KBIG + 2 * HH;  // mean segment
    const bool isGate = (n0 < 384);

    for (int kt = kc; kt < kc + GK / TSPLIT; kt += 64) {
        float4 a0 = *(const float4*)(Frow + kt + ac);
        float4 a1 = *(const float4*)(Frow + kt + ac + 32);
        float4 bv[4];
        #pragma unroll
        for (int jj = 0; jj < 4; ++jj) {
            int f = kt + jj * 16 + br;
            if (isGate) bv[jj] = *(const float4*)(Wg1 + (size_t)f * 384 + n0 + bc);
            else        bv[jj] = *(const float4*)(Wp  + (size_t)f * DD  + (n0 - 384) + bc);
        }
        __syncthreads();
        As[ac+0][ar] = a0.x * amul; As[ac+1][ar] = a0.y * amul;
        As[ac+2][ar] = a0.z * amul; As[ac+3][ar] = a0.w * amul;
        As[ac+32][ar] = a1.x * amul; As[ac+33][ar] = a1.y * amul;
        As[ac+34][ar] = a1.z * amul; As[ac+35][ar] = a1.w * amul;
        #pragma unroll
        for (int jj = 0; jj < 4; ++jj)
            *(float4*)&Bs[jj * 16 + br][bc] = bv[jj];
        __syncthreads();
        #pragma unroll
        for (int k = 0; k < 64; ++k) {
            float4 a = *(const float4*)&As[k][ty * 4];
            float2 bvv = *(const float2*)&Bs[k][tx * 2];
            acc[0][0] = fmaf(a.x, bvv.x, acc[0][0]);
            acc[0][1] = fmaf(a.x, bvv.y, acc[0][1]);
            acc[1][0] = fmaf(a.y, bvv.x, acc[1][0]);
            acc[1][1] = fmaf(a.y, bvv.y, acc[1][1]);
            acc[2][0] = fmaf(a.z, bvv.x, acc[2][0]);
            acc[2][1] = fmaf(a.z, bvv.y, acc[2][1]);
            acc[3][0] = fmaf(a.w, bvv.x, acc[3][0]);
            acc[3][1] = fmaf(a.w, bvv.y, acc[3][1]);
        }
    }
    #pragma unroll
    for (int r = 0; r < 4; ++r) {
        int row = m0 + ty * 4 + r;
        float2 st = make_float2(acc[r][0], acc[r][1]);
        *(float2*)&tpart[((size_t)blockIdx.z * (BB*MM) + row) * NTAIL + n0 + tx * 2] = st;
    }
}

// ---------------------------------------------------------------------------
// combine tail partials: gate cols -> tanh(+bg1)*wg2 block-reduce -> gate[row];
// embed cols -> +bp -> out_embeds. One block per row.
__global__ __launch_bounds__(256) void tail_fin(const float* __restrict__ tpart,
                                                const float* __restrict__ bg1,
                                                const float* __restrict__ wg2,
                                                const float* __restrict__ bg2,
                                                const float* __restrict__ bp,
                                                float* __restrict__ gate,
                                                float* __restrict__ out_embeds) {
    int row = blockIdx.x;
    int tid = threadIdx.x;
    float gpart = 0.f;
    #pragma unroll
    for (int cc = 0; cc < 3; ++cc) {
        int c = cc * 256 + tid;
        if (c >= NTAIL) break;
        float pre = tpart[(size_t)row * NTAIL + c]
                  + tpart[((size_t)(BB*MM) + row) * NTAIL + c]
                  + tpart[((size_t)(2*BB*MM) + row) * NTAIL + c];
        if (c < 384) {
            gpart += tanhf(pre + bg1[c]) * wg2[c];
        } else {
            int d = c - 384;
            out_embeds[(size_t)row * DD + d] = pre + bp[d];
        }
    }
    #pragma unroll
    for (int off = 32; off; off >>= 1) gpart += __shfl_xor(gpart, off);
    __shared__ float red[4];
    if ((tid & 63) == 0) red[tid >> 6] = gpart;
    __syncthreads();
    if (tid == 0) gate[row] = red[0] + red[1] + red[2] + red[3] + bg2[0];
}

// ---------------------------------------------------------------------------
// masks, masked softmax of gate, masked scores
__global__ __launch_bounds__(64) void finalize_kernel(const float* __restrict__ gate,
                                                      const float* __restrict__ tscoreF,
                                                      const int* __restrict__ nvalid,
                                                      float* __restrict__ out_masks,
                                                      float* __restrict__ out_attn,
                                                      float* __restrict__ out_scores) {
    int b = blockIdx.x;
    int t = threadIdx.x;
    bool live = (t < MM);
    bool maskon = live && (t < nvalid[b]);
    float g = maskon ? gate[b * MM + t] : -INFINITY;
    float mx = g;
    #pragma unroll
    for (int off = 16; off; off >>= 1) mx = fmaxf(mx, __shfl_xor(mx, off));
    float e = (g == -INFINITY) ? 0.f : expf(g - mx);
    float ssum = e;
    #pragma unroll
    for (int off = 16; off; off >>= 1) ssum += __shfl_xor(ssum, off);
    if (live) {
        out_masks[b * MM + t]  = maskon ? 1.0f : 0.0f;
        out_attn[b * MM + t]   = e / ssum;
        out_scores[b * MM + t] = maskon ? tscoreF[b * MM + t] : -INFINITY;
    }
}

// ---------------------------------------------------------------------------
extern "C" void kernel_launch(void* const* d_in, const int* in_sizes, int n_in,
                              void* d_out, int out_size, void* d_ws, size_t ws_size,
                              hipStream_t stream) {
    const float* hidden = (const float*)d_in[0];
    const int*   amask  = (const int*)  d_in[1];
    const float* W1     = (const float*)d_in[2];
    const float* b1     = (const float*)d_in[3];
    const float* w2     = (const float*)d_in[4];
    const float* b2     = (const float*)d_in[5];
    const float* Wg1    = (const float*)d_in[6];
    const float* bg1    = (const float*)d_in[7];
    const float* wg2    = (const float*)d_in[8];
    const float* bg2    = (const float*)d_in[9];
    const float* Wp     = (const float*)d_in[10];
    const float* bp     = (const float*)d_in[11];

    float* out = (float*)d_out;
    float* out_embeds = out;                       // 8*32*256 = 65536
    float* out_masks  = out + 65536;               // 256
    float* out_attn   = out + 65792;               // 256
    float* out_scores = out + 66048;               // 256

    // workspace layout
    unsigned short* A0  = (unsigned short*)d_ws;               // 4096*768 bf16
    unsigned short* B0  = A0 + (size_t)BL * GK;                // 2304*768 bf16
    unsigned short* XOh = B0 + (size_t)NCAT * GK;              // 4096*2304 bf16 (18.9 MB)
    float* scbuf = (float*)(XOh + (size_t)BL * NCAT);          // 8*2560
    int*   cidx  = (int*)(scbuf + (size_t)BB * NSC);           // 320
    int*   selc  = cidx + NCTOT;                               // 256
    float* tsF   = (float*)(selc + BB * MM);                   // 256
    float* cscore = tsF + BB * MM;                             // 320
    int*   lengths = (int*)(cscore + NCTOT);                   // 8
    int*   nvalid  = lengths + BB;                             // 8
    // aliased into XOh region (dead after topk): 2.9+5.9+2.0 MB < 18.9 MB
    float* Z        = (float*)XOh;                             // 320*2304
    float* pre_part = Z + (size_t)NCTOT * KBIG;                // 6*320*768
    float* tpart    = pre_part + (size_t)RSPLIT * NCTOT * HH;  // 3*256*640
    float* gate     = tpart + (size_t)TSPLIT * BB * MM * NTAIL;// 256

    prep_all<<<3072 + 1728 + BB, 256, 0, stream>>>(hidden, amask, W1, A0, B0,
                                                   lengths, nvalid);

    {
        dim3 grid(BL / 128, NCAT / 128);   // 32 x 18
        gemm_cheap<<<grid, 256, 0, stream>>>(A0, B0, XOh);
    }

    score_kernel<<<(BL * 64) / 256, 256, 0, stream>>>(XOh, b1, w2, b2, lengths, scbuf);

    topk_select<<<BB, 64, 0, stream>>>(scbuf, cidx);

    zgather<<<NCTOT, 256, 0, stream>>>(hidden, cidx, Z);

    {
        dim3 grid(NCTOT / 32, HH / 64, RSPLIT);    // 10 x 12 x 6
        rescore_part<<<grid, 256, 0, stream>>>(Z, W1, pre_part);
    }

    rescore_fin<<<NCTOT, 256, 0, stream>>>(pre_part, b1, w2, b2, cscore);

    rerank<<<BB, 64, 0, stream>>>(cscore, cidx, selc, tsF);

    {
        dim3 grid(BB * MM / 32, NTAIL / 64, TSPLIT);   // 8 x 10 x 3
        tail_part<<<grid, 256, 0, stream>>>(Z, selc, nvalid, Wg1, Wp, tpart);
    }

    tail_fin<<<BB * MM, 256, 0, stream>>>(tpart, bg1, wg2, bg2, bp,
                                          gate, out_embeds);

    finalize_kernel<<<BB, 64, 0, stream>>>(gate, tsF, nvalid,
                                           out_masks, out_attn, out_scores);
}